// Round 1
// baseline (576.506 us; speedup 1.0000x reference)
//
#include <hip/hip_runtime.h>

constexpr int D = 128;
constexpr int H = 256;
constexpr float EPS = 1e-5f;

static __device__ __forceinline__ void atomAddF(float* p, float v) {
#if defined(__HIP_PLATFORM_AMD__)
    unsafeAtomicAdd(p, v);   // native global_atomic_add_f32
#else
    atomicAdd(p, v);
#endif
}

// Fused conv MLP: conv = LN2( relu(LN1(x@W1 + b1)) @ W2 + b2 )
// 32 rows per block; each wave owns 8 rows end-to-end (no barriers).
// Lane owns 4 consecutive cols in phase 1 (H=256) and 2 in phase 2 (D=128).
__global__ __launch_bounds__(256) void conv_mlp_kernel(
    const float* __restrict__ x,
    const float* __restrict__ W1, const float* __restrict__ b1,
    const float* __restrict__ g1, const float* __restrict__ be1,
    const float* __restrict__ W2, const float* __restrict__ b2,
    const float* __restrict__ g2, const float* __restrict__ be2,
    float* __restrict__ conv, int N)
{
    __shared__ float Xs[32][D];   // 16 KB
    __shared__ float Hs[32][H];   // 32 KB
    const int wv    = threadIdx.x >> 6;
    const int lane  = threadIdx.x & 63;
    const int rbase = wv * 8;
    const int row0  = blockIdx.x * 32 + rbase;

    // Load this wave's 8 rows of x into LDS (wave-private -> no __syncthreads).
    {
        const float4* src = (const float4*)(x + (size_t)row0 * D);
        float4* dst = (float4*)(&Xs[rbase][0]);
        if (row0 + 8 <= N) {
            #pragma unroll
            for (int i = 0; i < 4; ++i) dst[lane + 64*i] = src[lane + 64*i];
        } else {
            #pragma unroll
            for (int i = 0; i < 4; ++i) {
                int idx = lane + 64*i;     // float4 index within 8x128 tile
                int r = idx >> 5;          // 32 float4 per row
                float4 z = make_float4(0.f,0.f,0.f,0.f);
                dst[idx] = (row0 + r < N) ? src[idx] : z;
            }
        }
    }

    // ---------- phase 1: S = x @ W1 + b1 ; h = relu(LN1(S)) ----------
    const int c4 = lane * 4;
    float acc[8][4];
    #pragma unroll
    for (int r = 0; r < 8; ++r) {
        acc[r][0] = 0.f; acc[r][1] = 0.f; acc[r][2] = 0.f; acc[r][3] = 0.f;
    }
    for (int k = 0; k < D; k += 4) {
        // one full W1 row (1KB) per coalesced wave load
        float4 wa = *(const float4*)(W1 + (size_t)(k+0)*H + c4);
        float4 wb = *(const float4*)(W1 + (size_t)(k+1)*H + c4);
        float4 wc = *(const float4*)(W1 + (size_t)(k+2)*H + c4);
        float4 wd = *(const float4*)(W1 + (size_t)(k+3)*H + c4);
        #pragma unroll
        for (int r = 0; r < 8; ++r) {
            float4 xv = *(const float4*)(&Xs[rbase + r][k]);   // broadcast ds_read_b128
            acc[r][0] += xv.x*wa.x + xv.y*wb.x + xv.z*wc.x + xv.w*wd.x;
            acc[r][1] += xv.x*wa.y + xv.y*wb.y + xv.z*wc.y + xv.w*wd.y;
            acc[r][2] += xv.x*wa.z + xv.y*wb.z + xv.z*wc.z + xv.w*wd.z;
            acc[r][3] += xv.x*wa.w + xv.y*wb.w + xv.z*wc.w + xv.w*wd.w;
        }
    }
    {
        float4 b1v  = *(const float4*)(b1  + c4);
        float4 g1v  = *(const float4*)(g1  + c4);
        float4 be1v = *(const float4*)(be1 + c4);
        #pragma unroll
        for (int r = 0; r < 8; ++r) {
            float v0 = acc[r][0] + b1v.x;
            float v1 = acc[r][1] + b1v.y;
            float v2 = acc[r][2] + b1v.z;
            float v3 = acc[r][3] + b1v.w;
            float s1 = v0+v1+v2+v3;
            float s2 = v0*v0+v1*v1+v2*v2+v3*v3;
            #pragma unroll
            for (int o = 1; o < 64; o <<= 1) {
                s1 += __shfl_xor(s1, o);
                s2 += __shfl_xor(s2, o);
            }
            float mu  = s1 * (1.f/H);
            float var = s2 * (1.f/H) - mu*mu;
            float rs  = rsqrtf(var + EPS);
            float h0 = fmaxf((v0-mu)*rs*g1v.x + be1v.x, 0.f);
            float h1 = fmaxf((v1-mu)*rs*g1v.y + be1v.y, 0.f);
            float h2 = fmaxf((v2-mu)*rs*g1v.z + be1v.z, 0.f);
            float h3 = fmaxf((v3-mu)*rs*g1v.w + be1v.w, 0.f);
            *(float4*)(&Hs[rbase + r][c4]) = make_float4(h0,h1,h2,h3);
        }
    }

    // ---------- phase 2: C = h @ W2 + b2 ; conv = LN2(C) ----------
    const int c2 = lane * 2;
    float acc2[8][2];
    #pragma unroll
    for (int r = 0; r < 8; ++r) { acc2[r][0] = 0.f; acc2[r][1] = 0.f; }
    for (int k = 0; k < H; k += 4) {
        float2 wa = *(const float2*)(W2 + (size_t)(k+0)*D + c2);
        float2 wb = *(const float2*)(W2 + (size_t)(k+1)*D + c2);
        float2 wc = *(const float2*)(W2 + (size_t)(k+2)*D + c2);
        float2 wd = *(const float2*)(W2 + (size_t)(k+3)*D + c2);
        #pragma unroll
        for (int r = 0; r < 8; ++r) {
            float4 hv = *(const float4*)(&Hs[rbase + r][k]);
            acc2[r][0] += hv.x*wa.x + hv.y*wb.x + hv.z*wc.x + hv.w*wd.x;
            acc2[r][1] += hv.x*wa.y + hv.y*wb.y + hv.z*wc.y + hv.w*wd.y;
        }
    }
    {
        float2 b2v  = *(const float2*)(b2  + c2);
        float2 g2v  = *(const float2*)(g2  + c2);
        float2 be2v = *(const float2*)(be2 + c2);
        #pragma unroll
        for (int r = 0; r < 8; ++r) {
            float v0 = acc2[r][0] + b2v.x;
            float v1 = acc2[r][1] + b2v.y;
            float s1 = v0+v1;
            float s2 = v0*v0+v1*v1;
            #pragma unroll
            for (int o = 1; o < 64; o <<= 1) {
                s1 += __shfl_xor(s1, o);
                s2 += __shfl_xor(s2, o);
            }
            float mu  = s1 * (1.f/D);
            float var = s2 * (1.f/D) - mu*mu;
            float rs  = rsqrtf(var + EPS);
            float o0 = (v0-mu)*rs*g2v.x + be2v.x;
            float o1 = (v1-mu)*rs*g2v.y + be2v.y;
            if (row0 + r < N)
                *(float2*)(conv + (size_t)(row0 + r)*D + c2) = make_float2(o0, o1);
        }
    }
}

// agg = x  (also serves as the per-call zeroing of the accumulator)
__global__ __launch_bounds__(256) void init_agg_kernel(
    const float* __restrict__ x, float* __restrict__ agg, int n4)
{
    int i = blockIdx.x * blockDim.x + threadIdx.x;
    if (i < n4) ((float4*)agg)[i] = ((const float4*)x)[i];
}

// agg[src] += conv[dst] * edge_attr[e]   (2 edges per 256-thread block)
__global__ __launch_bounds__(256) void scatter_kernel(
    const float* __restrict__ conv, const float* __restrict__ eattr,
    const int* __restrict__ eidx, float* __restrict__ agg, int E)
{
    int e = blockIdx.x * 2 + (threadIdx.x >> 7);
    if (e >= E) return;
    int d   = threadIdx.x & 127;
    int src = eidx[e];
    int dst = eidx[E + e];
    float v = conv[(size_t)dst * D + d] * eattr[(size_t)e * D + d];
    atomAddF(&agg[(size_t)src * D + d], v);
}

// out = LN(agg) with g_out/b_out ; one wave per row, 2 elems per lane
__global__ __launch_bounds__(256) void final_ln_kernel(
    const float* __restrict__ agg,
    const float* __restrict__ g, const float* __restrict__ b,
    float* __restrict__ out, int N)
{
    int row  = blockIdx.x * 4 + (threadIdx.x >> 6);
    if (row >= N) return;
    int lane = threadIdx.x & 63;
    float2 v = *(const float2*)(agg + (size_t)row * D + lane*2);
    float s1 = v.x + v.y;
    float s2 = v.x*v.x + v.y*v.y;
    #pragma unroll
    for (int o = 1; o < 64; o <<= 1) {
        s1 += __shfl_xor(s1, o);
        s2 += __shfl_xor(s2, o);
    }
    float mu  = s1 * (1.f/D);
    float var = s2 * (1.f/D) - mu*mu;
    float rs  = rsqrtf(var + EPS);
    float2 gv = *(const float2*)(g + lane*2);
    float2 bv = *(const float2*)(b + lane*2);
    float2 o2;
    o2.x = (v.x - mu)*rs*gv.x + bv.x;
    o2.y = (v.y - mu)*rs*gv.y + bv.y;
    *(float2*)(out + (size_t)row * D + lane*2) = o2;
}

extern "C" void kernel_launch(void* const* d_in, const int* in_sizes, int n_in,
                              void* d_out, int out_size, void* d_ws, size_t ws_size,
                              hipStream_t stream) {
    const float* x     = (const float*)d_in[0];
    const int*   eidx  = (const int*)  d_in[1];
    const float* eattr = (const float*)d_in[2];
    const float* W1    = (const float*)d_in[3];
    const float* b1    = (const float*)d_in[4];
    const float* g1    = (const float*)d_in[5];
    const float* be1   = (const float*)d_in[6];
    const float* W2    = (const float*)d_in[7];
    const float* b2    = (const float*)d_in[8];
    const float* g2    = (const float*)d_in[9];
    const float* be2   = (const float*)d_in[10];
    const float* g_out = (const float*)d_in[11];
    const float* b_out = (const float*)d_in[12];

    const int N = in_sizes[0] / D;   // 100000
    const int E = in_sizes[1] / 2;   // 640000

    float* out  = (float*)d_out;
    float* conv = out;               // use d_out as scratch for conv (overwritten by final_ln)
    float* agg  = (float*)d_ws;      // N*D floats = 51.2 MB

    // 1) conv = MLP(x)
    conv_mlp_kernel<<<(N + 31) / 32, 256, 0, stream>>>(
        x, W1, b1, g1, be1, W2, b2, g2, be2, conv, N);

    // 2) agg = x
    int n4 = (N * D) / 4;
    init_agg_kernel<<<(n4 + 255) / 256, 256, 0, stream>>>(x, agg, n4);

    // 3) agg[src] += conv[dst] * edge_attr
    scatter_kernel<<<(E + 1) / 2, 256, 0, stream>>>(conv, eattr, eidx, agg, E);

    // 4) out = LN(agg)
    final_ln_kernel<<<(N + 3) / 4, 256, 0, stream>>>(agg, g_out, b_out, out, N);
}

// Round 2
// 455.665 us; speedup vs baseline: 1.2652x; 1.2652x over previous
//
#include <hip/hip_runtime.h>

constexpr int D = 128;
constexpr int H = 256;
constexpr float EPS = 1e-5f;

static __device__ __forceinline__ void atomAddF(float* p, float v) {
#if defined(__HIP_PLATFORM_AMD__)
    unsafeAtomicAdd(p, v);   // native global_atomic_add_f32
#else
    atomicAdd(p, v);
#endif
}

// ---------------------------------------------------------------------------
// Fused conv MLP: conv = LN2( relu(LN1(x@W1 + b1)) @ W2 + b2 )
// 32 rows per block; each wave owns 8 rows end-to-end (no barriers).
// ---------------------------------------------------------------------------
__global__ __launch_bounds__(256) void conv_mlp_kernel(
    const float* __restrict__ x,
    const float* __restrict__ W1, const float* __restrict__ b1,
    const float* __restrict__ g1, const float* __restrict__ be1,
    const float* __restrict__ W2, const float* __restrict__ b2,
    const float* __restrict__ g2, const float* __restrict__ be2,
    float* __restrict__ conv, int N)
{
    __shared__ float Xs[32][D];   // 16 KB
    __shared__ float Hs[32][H];   // 32 KB
    const int wv    = threadIdx.x >> 6;
    const int lane  = threadIdx.x & 63;
    const int rbase = wv * 8;
    const int row0  = blockIdx.x * 32 + rbase;

    {
        const float4* src = (const float4*)(x + (size_t)row0 * D);
        float4* dst = (float4*)(&Xs[rbase][0]);
        if (row0 + 8 <= N) {
            #pragma unroll
            for (int i = 0; i < 4; ++i) dst[lane + 64*i] = src[lane + 64*i];
        } else {
            #pragma unroll
            for (int i = 0; i < 4; ++i) {
                int idx = lane + 64*i;
                int r = idx >> 5;
                float4 z = make_float4(0.f,0.f,0.f,0.f);
                dst[idx] = (row0 + r < N) ? src[idx] : z;
            }
        }
    }

    // ---------- phase 1: S = x @ W1 + b1 ; h = relu(LN1(S)) ----------
    const int c4 = lane * 4;
    float acc[8][4];
    #pragma unroll
    for (int r = 0; r < 8; ++r) {
        acc[r][0] = 0.f; acc[r][1] = 0.f; acc[r][2] = 0.f; acc[r][3] = 0.f;
    }
    for (int k = 0; k < D; k += 4) {
        float4 wa = *(const float4*)(W1 + (size_t)(k+0)*H + c4);
        float4 wb = *(const float4*)(W1 + (size_t)(k+1)*H + c4);
        float4 wc = *(const float4*)(W1 + (size_t)(k+2)*H + c4);
        float4 wd = *(const float4*)(W1 + (size_t)(k+3)*H + c4);
        #pragma unroll
        for (int r = 0; r < 8; ++r) {
            float4 xv = *(const float4*)(&Xs[rbase + r][k]);
            acc[r][0] += xv.x*wa.x + xv.y*wb.x + xv.z*wc.x + xv.w*wd.x;
            acc[r][1] += xv.x*wa.y + xv.y*wb.y + xv.z*wc.y + xv.w*wd.y;
            acc[r][2] += xv.x*wa.z + xv.y*wb.z + xv.z*wc.z + xv.w*wd.z;
            acc[r][3] += xv.x*wa.w + xv.y*wb.w + xv.z*wc.w + xv.w*wd.w;
        }
    }
    {
        float4 b1v  = *(const float4*)(b1  + c4);
        float4 g1v  = *(const float4*)(g1  + c4);
        float4 be1v = *(const float4*)(be1 + c4);
        #pragma unroll
        for (int r = 0; r < 8; ++r) {
            float v0 = acc[r][0] + b1v.x;
            float v1 = acc[r][1] + b1v.y;
            float v2 = acc[r][2] + b1v.z;
            float v3 = acc[r][3] + b1v.w;
            float s1 = v0+v1+v2+v3;
            float s2 = v0*v0+v1*v1+v2*v2+v3*v3;
            #pragma unroll
            for (int o = 1; o < 64; o <<= 1) {
                s1 += __shfl_xor(s1, o);
                s2 += __shfl_xor(s2, o);
            }
            float mu  = s1 * (1.f/H);
            float var = s2 * (1.f/H) - mu*mu;
            float rs  = rsqrtf(var + EPS);
            float h0 = fmaxf((v0-mu)*rs*g1v.x + be1v.x, 0.f);
            float h1 = fmaxf((v1-mu)*rs*g1v.y + be1v.y, 0.f);
            float h2 = fmaxf((v2-mu)*rs*g1v.z + be1v.z, 0.f);
            float h3 = fmaxf((v3-mu)*rs*g1v.w + be1v.w, 0.f);
            *(float4*)(&Hs[rbase + r][c4]) = make_float4(h0,h1,h2,h3);
        }
    }

    // ---------- phase 2: C = h @ W2 + b2 ; conv = LN2(C) ----------
    const int c2 = lane * 2;
    float acc2[8][2];
    #pragma unroll
    for (int r = 0; r < 8; ++r) { acc2[r][0] = 0.f; acc2[r][1] = 0.f; }
    for (int k = 0; k < H; k += 4) {
        float2 wa = *(const float2*)(W2 + (size_t)(k+0)*D + c2);
        float2 wb = *(const float2*)(W2 + (size_t)(k+1)*D + c2);
        float2 wc = *(const float2*)(W2 + (size_t)(k+2)*D + c2);
        float2 wd = *(const float2*)(W2 + (size_t)(k+3)*D + c2);
        #pragma unroll
        for (int r = 0; r < 8; ++r) {
            float4 hv = *(const float4*)(&Hs[rbase + r][k]);
            acc2[r][0] += hv.x*wa.x + hv.y*wb.x + hv.z*wc.x + hv.w*wd.x;
            acc2[r][1] += hv.x*wa.y + hv.y*wb.y + hv.z*wc.y + hv.w*wd.y;
        }
    }
    {
        float2 b2v  = *(const float2*)(b2  + c2);
        float2 g2v  = *(const float2*)(g2  + c2);
        float2 be2v = *(const float2*)(be2 + c2);
        #pragma unroll
        for (int r = 0; r < 8; ++r) {
            float v0 = acc2[r][0] + b2v.x;
            float v1 = acc2[r][1] + b2v.y;
            float s1 = v0+v1;
            float s2 = v0*v0+v1*v1;
            #pragma unroll
            for (int o = 1; o < 64; o <<= 1) {
                s1 += __shfl_xor(s1, o);
                s2 += __shfl_xor(s2, o);
            }
            float mu  = s1 * (1.f/D);
            float var = s2 * (1.f/D) - mu*mu;
            float rs  = rsqrtf(var + EPS);
            float o0 = (v0-mu)*rs*g2v.x + be2v.x;
            float o1 = (v1-mu)*rs*g2v.y + be2v.y;
            if (row0 + r < N)
                *(float2*)(conv + (size_t)(row0 + r)*D + c2) = make_float2(o0, o1);
        }
    }
}

// ---------------------------------------------------------------------------
// CSR build: zero -> histogram -> 3-step exclusive scan -> fill permutation
// ---------------------------------------------------------------------------
__global__ __launch_bounds__(256) void zero_int_kernel(int* __restrict__ p, int n) {
    int i = blockIdx.x * blockDim.x + threadIdx.x;
    if (i < n) p[i] = 0;
}

__global__ __launch_bounds__(256) void hist_kernel(
    const int* __restrict__ eidx, int* __restrict__ counts, int E)
{
    int e = blockIdx.x * blockDim.x + threadIdx.x;
    if (e < E) atomicAdd(&counts[eidx[e]], 1);
}

// per-block exclusive scan over 1024 elems (256 thr x 4); block total -> bsums
__global__ __launch_bounds__(256) void scan1_kernel(
    const int* __restrict__ counts, int* __restrict__ row_start,
    int* __restrict__ bsums, int N)
{
    __shared__ int sd[256];
    int t  = threadIdx.x;
    int i0 = blockIdx.x * 1024 + t * 4;
    int c0 = (i0+0 < N) ? counts[i0+0] : 0;
    int c1 = (i0+1 < N) ? counts[i0+1] : 0;
    int c2 = (i0+2 < N) ? counts[i0+2] : 0;
    int c3 = (i0+3 < N) ? counts[i0+3] : 0;
    int s  = c0 + c1 + c2 + c3;
    sd[t] = s;
    __syncthreads();
    #pragma unroll
    for (int off = 1; off < 256; off <<= 1) {
        int v = (t >= off) ? sd[t - off] : 0;
        __syncthreads();
        sd[t] += v;
        __syncthreads();
    }
    int ex = sd[t] - s;            // exclusive prefix of this thread
    if (i0+0 < N) row_start[i0+0] = ex;
    if (i0+1 < N) row_start[i0+1] = ex + c0;
    if (i0+2 < N) row_start[i0+2] = ex + c0 + c1;
    if (i0+3 < N) row_start[i0+3] = ex + c0 + c1 + c2;
    if (t == 255) bsums[blockIdx.x] = sd[255];
}

// single-block exclusive scan of block sums (NB <= 128)
__global__ __launch_bounds__(128) void scan2_kernel(int* __restrict__ bsums, int NB)
{
    __shared__ int sd[128];
    int t = threadIdx.x;
    int v = (t < NB) ? bsums[t] : 0;
    sd[t] = v;
    __syncthreads();
    #pragma unroll
    for (int off = 1; off < 128; off <<= 1) {
        int u = (t >= off) ? sd[t - off] : 0;
        __syncthreads();
        sd[t] += u;
        __syncthreads();
    }
    if (t < NB) bsums[t] = sd[t] - v;
}

// add block offsets; write final row_start and cursor copy
__global__ __launch_bounds__(256) void scan3_kernel(
    int* __restrict__ row_start, const int* __restrict__ bsums,
    int* __restrict__ cursor, int N)
{
    int i = blockIdx.x * blockDim.x + threadIdx.x;
    if (i < N) {
        int r = row_start[i] + bsums[i >> 10];
        row_start[i] = r;
        cursor[i]    = r;
    }
}

__global__ __launch_bounds__(256) void fill_kernel(
    const int* __restrict__ eidx, int* __restrict__ cursor,
    int* __restrict__ eord, int E)
{
    int e = blockIdx.x * blockDim.x + threadIdx.x;
    if (e < E) {
        int p = atomicAdd(&cursor[eidx[e]], 1);
        eord[p] = e;
    }
}

// ---------------------------------------------------------------------------
// Fused gather + final LN: out[v] = LN( x[v] + sum_{e: src=v} conv[dst]*eattr[e] )
// One wave per node, 2 floats per lane.
// ---------------------------------------------------------------------------
__global__ __launch_bounds__(256) void gather_ln_kernel(
    const float* __restrict__ x, const float* __restrict__ conv,
    const float* __restrict__ eattr, const int* __restrict__ eidx,
    const int* __restrict__ row_start, const int* __restrict__ eord,
    const float* __restrict__ g, const float* __restrict__ b,
    float* __restrict__ out, int N, int E)
{
    int node = blockIdx.x * 4 + (threadIdx.x >> 6);
    if (node >= N) return;
    int lane = threadIdx.x & 63;
    const int c2 = lane * 2;

    float2 acc = *(const float2*)(x + (size_t)node * D + c2);
    int j  = row_start[node];
    int je = (node + 1 < N) ? row_start[node + 1] : E;

    // unroll by 2 edges for ILP on the dependent load chains
    for (; j + 1 < je; j += 2) {
        int e0 = eord[j], e1 = eord[j + 1];
        int d0 = eidx[E + e0], d1 = eidx[E + e1];
        float2 ca = *(const float2*)(conv  + (size_t)d0 * D + c2);
        float2 aa = *(const float2*)(eattr + (size_t)e0 * D + c2);
        float2 cb = *(const float2*)(conv  + (size_t)d1 * D + c2);
        float2 ab = *(const float2*)(eattr + (size_t)e1 * D + c2);
        acc.x += ca.x * aa.x; acc.y += ca.y * aa.y;
        acc.x += cb.x * ab.x; acc.y += cb.y * ab.y;
    }
    if (j < je) {
        int e0 = eord[j];
        int d0 = eidx[E + e0];
        float2 ca = *(const float2*)(conv  + (size_t)d0 * D + c2);
        float2 aa = *(const float2*)(eattr + (size_t)e0 * D + c2);
        acc.x += ca.x * aa.x; acc.y += ca.y * aa.y;
    }

    float s1 = acc.x + acc.y;
    float s2 = acc.x*acc.x + acc.y*acc.y;
    #pragma unroll
    for (int o = 1; o < 64; o <<= 1) {
        s1 += __shfl_xor(s1, o);
        s2 += __shfl_xor(s2, o);
    }
    float mu  = s1 * (1.f/D);
    float var = s2 * (1.f/D) - mu*mu;
    float rs  = rsqrtf(var + EPS);
    float2 gv = *(const float2*)(g + c2);
    float2 bv = *(const float2*)(b + c2);
    float2 o2;
    o2.x = (acc.x - mu)*rs*gv.x + bv.x;
    o2.y = (acc.y - mu)*rs*gv.y + bv.y;
    *(float2*)(out + (size_t)node * D + c2) = o2;
}

// ---------------------------------------------------------------------------
// Fallback path (round-1 atomics) if ws_size is too small for CSR layout
// ---------------------------------------------------------------------------
__global__ __launch_bounds__(256) void init_agg_kernel(
    const float* __restrict__ x, float* __restrict__ agg, int n4)
{
    int i = blockIdx.x * blockDim.x + threadIdx.x;
    if (i < n4) ((float4*)agg)[i] = ((const float4*)x)[i];
}

__global__ __launch_bounds__(256) void scatter_kernel(
    const float* __restrict__ conv, const float* __restrict__ eattr,
    const int* __restrict__ eidx, float* __restrict__ agg, int E)
{
    int e = blockIdx.x * 2 + (threadIdx.x >> 7);
    if (e >= E) return;
    int d   = threadIdx.x & 127;
    int src = eidx[e];
    int dst = eidx[E + e];
    float v = conv[(size_t)dst * D + d] * eattr[(size_t)e * D + d];
    atomAddF(&agg[(size_t)src * D + d], v);
}

__global__ __launch_bounds__(256) void final_ln_kernel(
    const float* __restrict__ agg,
    const float* __restrict__ g, const float* __restrict__ b,
    float* __restrict__ out, int N)
{
    int row  = blockIdx.x * 4 + (threadIdx.x >> 6);
    if (row >= N) return;
    int lane = threadIdx.x & 63;
    float2 v = *(const float2*)(agg + (size_t)row * D + lane*2);
    float s1 = v.x + v.y;
    float s2 = v.x*v.x + v.y*v.y;
    #pragma unroll
    for (int o = 1; o < 64; o <<= 1) {
        s1 += __shfl_xor(s1, o);
        s2 += __shfl_xor(s2, o);
    }
    float mu  = s1 * (1.f/D);
    float var = s2 * (1.f/D) - mu*mu;
    float rs  = rsqrtf(var + EPS);
    float2 gv = *(const float2*)(g + lane*2);
    float2 bv = *(const float2*)(b + lane*2);
    float2 o2;
    o2.x = (v.x - mu)*rs*gv.x + bv.x;
    o2.y = (v.y - mu)*rs*gv.y + bv.y;
    *(float2*)(out + (size_t)row * D + lane*2) = o2;
}

extern "C" void kernel_launch(void* const* d_in, const int* in_sizes, int n_in,
                              void* d_out, int out_size, void* d_ws, size_t ws_size,
                              hipStream_t stream) {
    const float* x     = (const float*)d_in[0];
    const int*   eidx  = (const int*)  d_in[1];
    const float* eattr = (const float*)d_in[2];
    const float* W1    = (const float*)d_in[3];
    const float* b1    = (const float*)d_in[4];
    const float* g1    = (const float*)d_in[5];
    const float* be1   = (const float*)d_in[6];
    const float* W2    = (const float*)d_in[7];
    const float* b2    = (const float*)d_in[8];
    const float* g2    = (const float*)d_in[9];
    const float* be2   = (const float*)d_in[10];
    const float* g_out = (const float*)d_in[11];
    const float* b_out = (const float*)d_in[12];

    const int N = in_sizes[0] / D;   // 100000
    const int E = in_sizes[1] / 2;   // 640000

    float* out = (float*)d_out;

    // CSR workspace layout in d_ws (all 256B-aligned):
    auto align_up = [](size_t v) { return (v + 255) & ~(size_t)255; };
    size_t convB  = align_up((size_t)N * D * sizeof(float));   // 51.2 MB
    size_t cntB   = align_up((size_t)N * sizeof(int));         // 400 KB (counts, later cursor)
    size_t rsB    = align_up((size_t)N * sizeof(int));         // 400 KB
    size_t bsB    = align_up(128 * sizeof(int));
    size_t eordB  = align_up((size_t)E * sizeof(int));         // 2.56 MB
    size_t need   = convB + cntB + rsB + bsB + eordB;

    if (ws_size >= need) {
        char* w = (char*)d_ws;
        float* conv      = (float*)(w);
        int*   counts    = (int*)(w + convB);            // reused as cursor
        int*   row_start = (int*)(w + convB + cntB);
        int*   bsums     = (int*)(w + convB + cntB + rsB);
        int*   eord      = (int*)(w + convB + cntB + rsB + bsB);

        conv_mlp_kernel<<<(N + 31) / 32, 256, 0, stream>>>(
            x, W1, b1, g1, be1, W2, b2, g2, be2, conv, N);

        zero_int_kernel<<<(N + 255) / 256, 256, 0, stream>>>(counts, N);
        hist_kernel<<<(E + 255) / 256, 256, 0, stream>>>(eidx, counts, E);

        int NB = (N + 1023) / 1024;   // 98
        scan1_kernel<<<NB, 256, 0, stream>>>(counts, row_start, bsums, N);
        scan2_kernel<<<1, 128, 0, stream>>>(bsums, NB);
        scan3_kernel<<<(N + 255) / 256, 256, 0, stream>>>(row_start, bsums, counts, N);

        fill_kernel<<<(E + 255) / 256, 256, 0, stream>>>(eidx, counts, eord, E);

        gather_ln_kernel<<<(N + 3) / 4, 256, 0, stream>>>(
            x, conv, eattr, eidx, row_start, eord, g_out, b_out, out, N, E);
    } else {
        // fallback: round-1 atomic path
        float* conv = out;
        float* agg  = (float*)d_ws;

        conv_mlp_kernel<<<(N + 31) / 32, 256, 0, stream>>>(
            x, W1, b1, g1, be1, W2, b2, g2, be2, conv, N);
        int n4 = (N * D) / 4;
        init_agg_kernel<<<(n4 + 255) / 256, 256, 0, stream>>>(x, agg, n4);
        scatter_kernel<<<(E + 1) / 2, 256, 0, stream>>>(conv, eattr, eidx, agg, E);
        final_ln_kernel<<<(N + 3) / 4, 256, 0, stream>>>(agg, g_out, b_out, out, N);
    }
}

// Round 4
// 237.300 us; speedup vs baseline: 2.4294x; 1.9202x over previous
//
#include <hip/hip_runtime.h>

constexpr int D = 128;
constexpr int H = 256;
constexpr float EPS = 1e-5f;

typedef __attribute__((ext_vector_type(8))) short   short8;
typedef __attribute__((ext_vector_type(8))) __bf16  bf16x8;   // 4 VGPRs
typedef __attribute__((ext_vector_type(4))) float   f32x4;

static __device__ __forceinline__ unsigned short f2bfu(float f) {
    unsigned u = __float_as_uint(f);
    return (unsigned short)((u + 0x7FFFu + ((u >> 16) & 1u)) >> 16);   // RNE
}
static __device__ __forceinline__ float bf2f(unsigned short u) {
    return __uint_as_float((unsigned)u << 16);
}

static __device__ __forceinline__ f32x4 mfma16x16x32(bf16x8 a, bf16x8 b, f32x4 c) {
    return __builtin_amdgcn_mfma_f32_16x16x32_bf16(a, b, c, 0, 0, 0);
}

// ---------------------------------------------------------------------------
// Pack W (K x Ncols fp32 row-major) into MFMA B-fragment order, bf16:
// Wp[((j*nt + t)*64 + lane)*8 + i] = bf16(W[(32t + (lane>>4)*8 + i)*Ncols + 16j + (lane&15)])
// ---------------------------------------------------------------------------
__global__ __launch_bounds__(256) void pack_w_kernel(
    const float* __restrict__ W, unsigned short* __restrict__ Wp, int K, int Ncols)
{
    int e = blockIdx.x * 256 + threadIdx.x;
    if (e >= K * Ncols) return;
    int i  = e & 7;
    int l  = (e >> 3) & 63;
    int jt = e >> 9;
    int nt = K >> 5;
    int j  = jt / nt;
    int t  = jt - j * nt;
    int k  = 32 * t + ((l >> 4) << 3) + i;
    int c  = 16 * j + (l & 15);
    Wp[e] = f2bfu(W[(size_t)k * Ncols + c]);
}

// ---------------------------------------------------------------------------
// conv = LN2( relu(LN1(x@W1 + b1)) @ W2 + b2 ), bf16 MFMA, output bf16.
// 64 rows/block, 4 waves, each wave owns 16 rows (no barriers).
// ---------------------------------------------------------------------------
__global__ __launch_bounds__(256) void conv_mlp_mfma(
    const float* __restrict__ x,
    const unsigned short* __restrict__ W1p, const float* __restrict__ b1,
    const float* __restrict__ g1, const float* __restrict__ be1,
    const unsigned short* __restrict__ W2p, const float* __restrict__ b2,
    const float* __restrict__ g2, const float* __restrict__ be2,
    unsigned short* __restrict__ convb, int N)
{
    __shared__ unsigned short Hs[64 * 256];   // 32 KB bf16, XOR-swizzled rows
    const int wv   = threadIdx.x >> 6;
    const int lane = threadIdx.x & 63;
    const int rrow = lane & 15;    // A row / B,C col index
    const int kgrp = lane >> 4;    // input k-group / C row-group
    const int r0   = blockIdx.x * 64 + wv * 16;

    // ---- A fragments for GEMM1 directly from global x (fp32 -> bf16) ----
    int arow = r0 + rrow; if (arow >= N) arow = N - 1;
    const float* xr = x + (size_t)arow * D + kgrp * 8;
    bf16x8 A1[4];
    #pragma unroll
    for (int t = 0; t < 4; ++t) {
        float4 fa = *(const float4*)(xr + t * 32);
        float4 fb = *(const float4*)(xr + t * 32 + 4);
        bf16x8 a;
        a[0] = (__bf16)fa.x; a[1] = (__bf16)fa.y; a[2] = (__bf16)fa.z; a[3] = (__bf16)fa.w;
        a[4] = (__bf16)fb.x; a[5] = (__bf16)fb.y; a[6] = (__bf16)fb.z; a[7] = (__bf16)fb.w;
        A1[t] = a;
    }

    // ---- GEMM1: S(16x256) = A(16x128) @ W1, 16 col-tiles x 4 K-tiles ----
    f32x4 acc[16];
    #pragma unroll
    for (int j = 0; j < 16; ++j) acc[j] = (f32x4){0.f, 0.f, 0.f, 0.f};
    const bf16x8* w1f = (const bf16x8*)W1p;
    #pragma unroll
    for (int j = 0; j < 16; ++j) {
        #pragma unroll
        for (int t = 0; t < 4; ++t) {
            bf16x8 B = w1f[(j * 4 + t) * 64 + lane];
            acc[j] = mfma16x16x32(A1[t], B, acc[j]);
        }
    }

    // ---- LN1 params (loaded after GEMM1 to cut peak VGPR) ----
    float b1r[16], g1r[16], be1r[16];
    #pragma unroll
    for (int j = 0; j < 16; ++j) {
        int c = 16 * j + rrow;
        b1r[j] = b1[c]; g1r[j] = g1[c]; be1r[j] = be1[c];
    }

    // ---- bias + LN1 stats (rows = kgrp*4 + r, cols spread over lane&15) ----
    float s1[4] = {0,0,0,0}, s2[4] = {0,0,0,0};
    #pragma unroll
    for (int j = 0; j < 16; ++j) {
        #pragma unroll
        for (int r = 0; r < 4; ++r) {
            float v = acc[j][r] + b1r[j];
            acc[j][r] = v;
            s1[r] += v; s2[r] += v * v;
        }
    }
    #pragma unroll
    for (int m = 1; m < 16; m <<= 1) {
        #pragma unroll
        for (int r = 0; r < 4; ++r) {
            s1[r] += __shfl_xor(s1[r], m);
            s2[r] += __shfl_xor(s2[r], m);
        }
    }

    // ---- LN1 + relu -> Hs (bf16, swizzled) ----
    #pragma unroll
    for (int r = 0; r < 4; ++r) {
        float mu  = s1[r] * (1.f / H);
        float var = s2[r] * (1.f / H) - mu * mu;
        float rs  = rsqrtf(var + EPS);
        int row = wv * 16 + kgrp * 4 + r;      // block-local row
        #pragma unroll
        for (int j = 0; j < 16; ++j) {
            float h = fmaxf((acc[j][r] - mu) * rs * g1r[j] + be1r[j], 0.f);
            int byte = (row << 9) + ((16 * j + rrow) << 1);
            byte ^= (row & 15) << 4;
            *(unsigned short*)((char*)Hs + byte) = f2bfu(h);
        }
    }

    // ---- A fragments for GEMM2 from Hs (swizzled 16B reads) ----
    bf16x8 A2[8];
    #pragma unroll
    for (int t = 0; t < 8; ++t) {
        int row  = wv * 16 + rrow;
        int byte = (row << 9) + ((t * 32 + kgrp * 8) << 1);
        byte ^= (row & 15) << 4;
        A2[t] = *(const bf16x8*)((const char*)Hs + byte);
    }

    // ---- GEMM2: C(16x128) = H(16x256) @ W2, 8 col-tiles x 8 K-tiles ----
    f32x4 acc2[8];
    #pragma unroll
    for (int j = 0; j < 8; ++j) acc2[j] = (f32x4){0.f, 0.f, 0.f, 0.f};
    const bf16x8* w2f = (const bf16x8*)W2p;
    #pragma unroll
    for (int j = 0; j < 8; ++j) {
        #pragma unroll
        for (int t = 0; t < 8; ++t) {
            bf16x8 B = w2f[(j * 8 + t) * 64 + lane];
            acc2[j] = mfma16x16x32(A2[t], B, acc2[j]);
        }
    }

    // ---- LN2 params ----
    float b2r[8], g2r[8], be2r[8];
    #pragma unroll
    for (int j = 0; j < 8; ++j) {
        int c = 16 * j + rrow;
        b2r[j] = b2[c]; g2r[j] = g2[c]; be2r[j] = be2[c];
    }

    // ---- bias + LN2 + store conv (bf16) ----
    float u1[4] = {0,0,0,0}, u2[4] = {0,0,0,0};
    #pragma unroll
    for (int j = 0; j < 8; ++j) {
        #pragma unroll
        for (int r = 0; r < 4; ++r) {
            float v = acc2[j][r] + b2r[j];
            acc2[j][r] = v;
            u1[r] += v; u2[r] += v * v;
        }
    }
    #pragma unroll
    for (int m = 1; m < 16; m <<= 1) {
        #pragma unroll
        for (int r = 0; r < 4; ++r) {
            u1[r] += __shfl_xor(u1[r], m);
            u2[r] += __shfl_xor(u2[r], m);
        }
    }
    #pragma unroll
    for (int r = 0; r < 4; ++r) {
        float mu  = u1[r] * (1.f / D);
        float var = u2[r] * (1.f / D) - mu * mu;
        float rs  = rsqrtf(var + EPS);
        int grow = r0 + kgrp * 4 + r;
        if (grow < N) {
            #pragma unroll
            for (int j = 0; j < 8; ++j) {
                float o = (acc2[j][r] - mu) * rs * g2r[j] + be2r[j];
                convb[(size_t)grow * D + 16 * j + rrow] = f2bfu(o);
            }
        }
    }
}

// ---------------------------------------------------------------------------
// CSR build: zero -> histogram -> 3-step exclusive scan -> fill permutation
// ---------------------------------------------------------------------------
__global__ __launch_bounds__(256) void zero_int_kernel(int* __restrict__ p, int n) {
    int i = blockIdx.x * blockDim.x + threadIdx.x;
    if (i < n) p[i] = 0;
}

__global__ __launch_bounds__(256) void hist_kernel(
    const int* __restrict__ eidx, int* __restrict__ counts, int E)
{
    int e = blockIdx.x * blockDim.x + threadIdx.x;
    if (e < E) atomicAdd(&counts[eidx[e]], 1);
}

__global__ __launch_bounds__(256) void scan1_kernel(
    const int* __restrict__ counts, int* __restrict__ row_start,
    int* __restrict__ bsums, int N)
{
    __shared__ int sd[256];
    int t  = threadIdx.x;
    int i0 = blockIdx.x * 1024 + t * 4;
    int c0 = (i0+0 < N) ? counts[i0+0] : 0;
    int c1 = (i0+1 < N) ? counts[i0+1] : 0;
    int c2 = (i0+2 < N) ? counts[i0+2] : 0;
    int c3 = (i0+3 < N) ? counts[i0+3] : 0;
    int s  = c0 + c1 + c2 + c3;
    sd[t] = s;
    __syncthreads();
    #pragma unroll
    for (int off = 1; off < 256; off <<= 1) {
        int v = (t >= off) ? sd[t - off] : 0;
        __syncthreads();
        sd[t] += v;
        __syncthreads();
    }
    int ex = sd[t] - s;
    if (i0+0 < N) row_start[i0+0] = ex;
    if (i0+1 < N) row_start[i0+1] = ex + c0;
    if (i0+2 < N) row_start[i0+2] = ex + c0 + c1;
    if (i0+3 < N) row_start[i0+3] = ex + c0 + c1 + c2;
    if (t == 255) bsums[blockIdx.x] = sd[255];
}

__global__ __launch_bounds__(128) void scan2_kernel(int* __restrict__ bsums, int NB)
{
    __shared__ int sd[128];
    int t = threadIdx.x;
    int v = (t < NB) ? bsums[t] : 0;
    sd[t] = v;
    __syncthreads();
    #pragma unroll
    for (int off = 1; off < 128; off <<= 1) {
        int u = (t >= off) ? sd[t - off] : 0;
        __syncthreads();
        sd[t] += u;
        __syncthreads();
    }
    if (t < NB) bsums[t] = sd[t] - v;
}

__global__ __launch_bounds__(256) void scan3_kernel(
    int* __restrict__ row_start, const int* __restrict__ bsums,
    int* __restrict__ cursor, int N)
{
    int i = blockIdx.x * blockDim.x + threadIdx.x;
    if (i < N) {
        int r = row_start[i] + bsums[i >> 10];
        row_start[i] = r;
        cursor[i]    = r;
    }
}

// edat[p] = {edge id, dst}
__global__ __launch_bounds__(256) void fill_kernel(
    const int* __restrict__ eidx, int* __restrict__ cursor,
    int2* __restrict__ edat, int E)
{
    int e = blockIdx.x * blockDim.x + threadIdx.x;
    if (e < E) {
        int s = eidx[e];
        int p = atomicAdd(&cursor[s], 1);
        edat[p] = make_int2(e, eidx[E + e]);
    }
}

// ---------------------------------------------------------------------------
// out[v] = LN( x[v] + sum_{e: src=v} conv_bf16[dst]*eattr[e] ), one wave/node
// ---------------------------------------------------------------------------
__global__ __launch_bounds__(256) void gather_ln_kernel(
    const float* __restrict__ x, const unsigned short* __restrict__ convb,
    const float* __restrict__ eattr,
    const int* __restrict__ row_start, const int2* __restrict__ edat,
    const float* __restrict__ g, const float* __restrict__ b,
    float* __restrict__ out, int N, int E)
{
    int node = blockIdx.x * 4 + (threadIdx.x >> 6);
    if (node >= N) return;
    int lane = threadIdx.x & 63;
    const int c2 = lane * 2;

    float2 acc = *(const float2*)(x + (size_t)node * D + c2);
    int j  = row_start[node];
    int je = (node + 1 < N) ? row_start[node + 1] : E;

    for (; j + 1 < je; j += 2) {
        int2 ea = edat[j], eb = edat[j + 1];
        ushort2 ca = *(const ushort2*)(convb + (size_t)ea.y * D + c2);
        float2  aa = *(const float2*)(eattr + (size_t)ea.x * D + c2);
        ushort2 cb = *(const ushort2*)(convb + (size_t)eb.y * D + c2);
        float2  ab = *(const float2*)(eattr + (size_t)eb.x * D + c2);
        acc.x += bf2f(ca.x) * aa.x; acc.y += bf2f(ca.y) * aa.y;
        acc.x += bf2f(cb.x) * ab.x; acc.y += bf2f(cb.y) * ab.y;
    }
    if (j < je) {
        int2 ea = edat[j];
        ushort2 ca = *(const ushort2*)(convb + (size_t)ea.y * D + c2);
        float2  aa = *(const float2*)(eattr + (size_t)ea.x * D + c2);
        acc.x += bf2f(ca.x) * aa.x; acc.y += bf2f(ca.y) * aa.y;
    }

    float s1 = acc.x + acc.y;
    float s2 = acc.x*acc.x + acc.y*acc.y;
    #pragma unroll
    for (int o = 1; o < 64; o <<= 1) {
        s1 += __shfl_xor(s1, o);
        s2 += __shfl_xor(s2, o);
    }
    float mu  = s1 * (1.f / D);
    float var = s2 * (1.f / D) - mu * mu;
    float rs  = rsqrtf(var + EPS);
    float2 gv = *(const float2*)(g + c2);
    float2 bv = *(const float2*)(b + c2);
    float2 o2;
    o2.x = (acc.x - mu) * rs * gv.x + bv.x;
    o2.y = (acc.y - mu) * rs * gv.y + bv.y;
    *(float2*)(out + (size_t)node * D + c2) = o2;
}

extern "C" void kernel_launch(void* const* d_in, const int* in_sizes, int n_in,
                              void* d_out, int out_size, void* d_ws, size_t ws_size,
                              hipStream_t stream) {
    const float* x     = (const float*)d_in[0];
    const int*   eidx  = (const int*)  d_in[1];
    const float* eattr = (const float*)d_in[2];
    const float* W1    = (const float*)d_in[3];
    const float* b1    = (const float*)d_in[4];
    const float* g1    = (const float*)d_in[5];
    const float* be1   = (const float*)d_in[6];
    const float* W2    = (const float*)d_in[7];
    const float* b2    = (const float*)d_in[8];
    const float* g2    = (const float*)d_in[9];
    const float* be2   = (const float*)d_in[10];
    const float* g_out = (const float*)d_in[11];
    const float* b_out = (const float*)d_in[12];

    const int N = in_sizes[0] / D;   // 100000
    const int E = in_sizes[1] / 2;   // 640000

    float* out = (float*)d_out;

    // workspace layout (256B aligned)
    auto align_up = [](size_t v) { return (v + 255) & ~(size_t)255; };
    size_t convB = align_up((size_t)N * D * sizeof(unsigned short));  // 25.6 MB
    size_t cntB  = align_up((size_t)N * sizeof(int));
    size_t rsB   = align_up((size_t)N * sizeof(int));
    size_t bsB   = align_up(128 * sizeof(int));
    size_t edB   = align_up((size_t)E * sizeof(int2));                // 5.12 MB
    size_t w1B   = align_up((size_t)D * H * sizeof(unsigned short));  // 64 KB

    char* w = (char*)d_ws;
    unsigned short* convb     = (unsigned short*)(w);
    int*            counts    = (int*)(w + convB);                 // reused as cursor
    int*            row_start = (int*)(w + convB + cntB);
    int*            bsums     = (int*)(w + convB + cntB + rsB);
    int2*           edat      = (int2*)(w + convB + cntB + rsB + bsB);
    unsigned short* W1p       = (unsigned short*)(w + convB + cntB + rsB + bsB + edB);
    unsigned short* W2p       = (unsigned short*)(w + convB + cntB + rsB + bsB + edB + w1B);

    // 1) pack weights into MFMA fragment order (bf16)
    pack_w_kernel<<<(D * H + 255) / 256, 256, 0, stream>>>(W1, W1p, D, H);
    pack_w_kernel<<<(H * D + 255) / 256, 256, 0, stream>>>(W2, W2p, H, D);

    // 2) conv = MLP(x) via bf16 MFMA
    conv_mlp_mfma<<<(N + 63) / 64, 256, 0, stream>>>(
        x, W1p, b1, g1, be1, W2p, b2, g2, be2, convb, N);

    // 3) CSR build
    zero_int_kernel<<<(N + 255) / 256, 256, 0, stream>>>(counts, N);
    hist_kernel<<<(E + 255) / 256, 256, 0, stream>>>(eidx, counts, E);
    int NB = (N + 1023) / 1024;
    scan1_kernel<<<NB, 256, 0, stream>>>(counts, row_start, bsums, N);
    scan2_kernel<<<1, 128, 0, stream>>>(bsums, NB);
    scan3_kernel<<<(N + 255) / 256, 256, 0, stream>>>(row_start, bsums, counts, N);
    fill_kernel<<<(E + 255) / 256, 256, 0, stream>>>(eidx, counts, edat, E);

    // 4) gather + final LN
    gather_ln_kernel<<<(N + 3) / 4, 256, 0, stream>>>(
        x, convb, eattr, row_start, edat, g_out, b_out, out, N, E);
}

// Round 5
// 230.191 us; speedup vs baseline: 2.5045x; 1.0309x over previous
//
#include <hip/hip_runtime.h>

constexpr int D = 128;
constexpr int H = 256;
constexpr float EPS = 1e-5f;

typedef __attribute__((ext_vector_type(8))) __bf16  bf16x8;   // 4 VGPRs
typedef __attribute__((ext_vector_type(4))) float   f32x4;

static __device__ __forceinline__ unsigned short f2bfu(float f) {
    unsigned u = __float_as_uint(f);
    return (unsigned short)((u + 0x7FFFu + ((u >> 16) & 1u)) >> 16);   // RNE
}
static __device__ __forceinline__ float bf2f(unsigned short u) {
    return __uint_as_float((unsigned)u << 16);
}

static __device__ __forceinline__ f32x4 mfma16x16x32(bf16x8 a, bf16x8 b, f32x4 c) {
    return __builtin_amdgcn_mfma_f32_16x16x32_bf16(a, b, c, 0, 0, 0);
}

// ---------------------------------------------------------------------------
// Pack W (K x Ncols fp32 row-major) into MFMA B-fragment order, bf16:
// Wp[((j*nt + t)*64 + lane)*8 + i] = bf16(W[(32t + (lane>>4)*8 + i)*Ncols + 16j + (lane&15)])
// ---------------------------------------------------------------------------
__global__ __launch_bounds__(256) void pack_w_kernel(
    const float* __restrict__ W, unsigned short* __restrict__ Wp, int K, int Ncols)
{
    int e = blockIdx.x * 256 + threadIdx.x;
    if (e >= K * Ncols) return;
    int i  = e & 7;
    int l  = (e >> 3) & 63;
    int jt = e >> 9;
    int nt = K >> 5;
    int j  = jt / nt;
    int t  = jt - j * nt;
    int k  = 32 * t + ((l >> 4) << 3) + i;
    int c  = 16 * j + (l & 15);
    Wp[e] = f2bfu(W[(size_t)k * Ncols + c]);
}

// ---------------------------------------------------------------------------
// conv = LN2( relu(LN1(x@W1 + b1)) @ W2 + b2 ), bf16 MFMA, output bf16.
// 64 rows/block, 4 waves, each wave owns 16 rows (no barriers).
// ---------------------------------------------------------------------------
__global__ __launch_bounds__(256) void conv_mlp_mfma(
    const float* __restrict__ x,
    const unsigned short* __restrict__ W1p, const float* __restrict__ b1,
    const float* __restrict__ g1, const float* __restrict__ be1,
    const unsigned short* __restrict__ W2p, const float* __restrict__ b2,
    const float* __restrict__ g2, const float* __restrict__ be2,
    unsigned short* __restrict__ convb, int N)
{
    __shared__ unsigned short Hs[64 * 256];   // 32 KB bf16, XOR-swizzled rows
    const int wv   = threadIdx.x >> 6;
    const int lane = threadIdx.x & 63;
    const int rrow = lane & 15;    // A row / B,C col index
    const int kgrp = lane >> 4;    // input k-group / C row-group
    const int r0   = blockIdx.x * 64 + wv * 16;

    // ---- A fragments for GEMM1 directly from global x (fp32 -> bf16) ----
    int arow = r0 + rrow; if (arow >= N) arow = N - 1;
    const float* xr = x + (size_t)arow * D + kgrp * 8;
    bf16x8 A1[4];
    #pragma unroll
    for (int t = 0; t < 4; ++t) {
        float4 fa = *(const float4*)(xr + t * 32);
        float4 fb = *(const float4*)(xr + t * 32 + 4);
        bf16x8 a;
        a[0] = (__bf16)fa.x; a[1] = (__bf16)fa.y; a[2] = (__bf16)fa.z; a[3] = (__bf16)fa.w;
        a[4] = (__bf16)fb.x; a[5] = (__bf16)fb.y; a[6] = (__bf16)fb.z; a[7] = (__bf16)fb.w;
        A1[t] = a;
    }

    // ---- GEMM1: S(16x256) = A(16x128) @ W1, 16 col-tiles x 4 K-tiles ----
    f32x4 acc[16];
    #pragma unroll
    for (int j = 0; j < 16; ++j) acc[j] = (f32x4){0.f, 0.f, 0.f, 0.f};
    const bf16x8* w1f = (const bf16x8*)W1p;
    #pragma unroll
    for (int j = 0; j < 16; ++j) {
        #pragma unroll
        for (int t = 0; t < 4; ++t) {
            bf16x8 B = w1f[(j * 4 + t) * 64 + lane];
            acc[j] = mfma16x16x32(A1[t], B, acc[j]);
        }
    }

    // ---- LN1 params (loaded after GEMM1 to cut peak VGPR) ----
    float b1r[16], g1r[16], be1r[16];
    #pragma unroll
    for (int j = 0; j < 16; ++j) {
        int c = 16 * j + rrow;
        b1r[j] = b1[c]; g1r[j] = g1[c]; be1r[j] = be1[c];
    }

    // ---- bias + LN1 stats (rows = kgrp*4 + r, cols spread over lane&15) ----
    float s1[4] = {0,0,0,0}, s2[4] = {0,0,0,0};
    #pragma unroll
    for (int j = 0; j < 16; ++j) {
        #pragma unroll
        for (int r = 0; r < 4; ++r) {
            float v = acc[j][r] + b1r[j];
            acc[j][r] = v;
            s1[r] += v; s2[r] += v * v;
        }
    }
    #pragma unroll
    for (int m = 1; m < 16; m <<= 1) {
        #pragma unroll
        for (int r = 0; r < 4; ++r) {
            s1[r] += __shfl_xor(s1[r], m);
            s2[r] += __shfl_xor(s2[r], m);
        }
    }

    // ---- LN1 + relu -> Hs (bf16, swizzled) ----
    #pragma unroll
    for (int r = 0; r < 4; ++r) {
        float mu  = s1[r] * (1.f / H);
        float var = s2[r] * (1.f / H) - mu * mu;
        float rs  = rsqrtf(var + EPS);
        int row = wv * 16 + kgrp * 4 + r;      // block-local row
        #pragma unroll
        for (int j = 0; j < 16; ++j) {
            float h = fmaxf((acc[j][r] - mu) * rs * g1r[j] + be1r[j], 0.f);
            int byte = (row << 9) + ((16 * j + rrow) << 1);
            byte ^= (row & 15) << 4;
            *(unsigned short*)((char*)Hs + byte) = f2bfu(h);
        }
    }

    // ---- A fragments for GEMM2 from Hs (swizzled 16B reads) ----
    bf16x8 A2[8];
    #pragma unroll
    for (int t = 0; t < 8; ++t) {
        int row  = wv * 16 + rrow;
        int byte = (row << 9) + ((t * 32 + kgrp * 8) << 1);
        byte ^= (row & 15) << 4;
        A2[t] = *(const bf16x8*)((const char*)Hs + byte);
    }

    // ---- GEMM2: C(16x128) = H(16x256) @ W2, 8 col-tiles x 8 K-tiles ----
    f32x4 acc2[8];
    #pragma unroll
    for (int j = 0; j < 8; ++j) acc2[j] = (f32x4){0.f, 0.f, 0.f, 0.f};
    const bf16x8* w2f = (const bf16x8*)W2p;
    #pragma unroll
    for (int j = 0; j < 8; ++j) {
        #pragma unroll
        for (int t = 0; t < 8; ++t) {
            bf16x8 B = w2f[(j * 8 + t) * 64 + lane];
            acc2[j] = mfma16x16x32(A2[t], B, acc2[j]);
        }
    }

    // ---- LN2 params ----
    float b2r[8], g2r[8], be2r[8];
    #pragma unroll
    for (int j = 0; j < 8; ++j) {
        int c = 16 * j + rrow;
        b2r[j] = b2[c]; g2r[j] = g2[c]; be2r[j] = be2[c];
    }

    // ---- bias + LN2 + store conv (bf16) ----
    float u1[4] = {0,0,0,0}, u2[4] = {0,0,0,0};
    #pragma unroll
    for (int j = 0; j < 8; ++j) {
        #pragma unroll
        for (int r = 0; r < 4; ++r) {
            float v = acc2[j][r] + b2r[j];
            acc2[j][r] = v;
            u1[r] += v; u2[r] += v * v;
        }
    }
    #pragma unroll
    for (int m = 1; m < 16; m <<= 1) {
        #pragma unroll
        for (int r = 0; r < 4; ++r) {
            u1[r] += __shfl_xor(u1[r], m);
            u2[r] += __shfl_xor(u2[r], m);
        }
    }
    #pragma unroll
    for (int r = 0; r < 4; ++r) {
        float mu  = u1[r] * (1.f / D);
        float var = u2[r] * (1.f / D) - mu * mu;
        float rs  = rsqrtf(var + EPS);
        int grow = r0 + kgrp * 4 + r;
        if (grow < N) {
            #pragma unroll
            for (int j = 0; j < 8; ++j) {
                float o = (acc2[j][r] - mu) * rs * g2r[j] + be2r[j];
                convb[(size_t)grow * D + 16 * j + rrow] = f2bfu(o);
            }
        }
    }
}

// ---------------------------------------------------------------------------
// CSR build: zero -> histogram -> 3-step exclusive scan -> fill permutation
// ---------------------------------------------------------------------------
__global__ __launch_bounds__(256) void zero_int_kernel(int* __restrict__ p, int n) {
    int i = blockIdx.x * blockDim.x + threadIdx.x;
    if (i < n) p[i] = 0;
}

__global__ __launch_bounds__(256) void hist_kernel(
    const int* __restrict__ eidx, int* __restrict__ counts, int E)
{
    int e = blockIdx.x * blockDim.x + threadIdx.x;
    if (e < E) atomicAdd(&counts[eidx[e]], 1);
}

__global__ __launch_bounds__(256) void scan1_kernel(
    const int* __restrict__ counts, int* __restrict__ row_start,
    int* __restrict__ bsums, int N)
{
    __shared__ int sd[256];
    int t  = threadIdx.x;
    int i0 = blockIdx.x * 1024 + t * 4;
    int c0 = (i0+0 < N) ? counts[i0+0] : 0;
    int c1 = (i0+1 < N) ? counts[i0+1] : 0;
    int c2 = (i0+2 < N) ? counts[i0+2] : 0;
    int c3 = (i0+3 < N) ? counts[i0+3] : 0;
    int s  = c0 + c1 + c2 + c3;
    sd[t] = s;
    __syncthreads();
    #pragma unroll
    for (int off = 1; off < 256; off <<= 1) {
        int v = (t >= off) ? sd[t - off] : 0;
        __syncthreads();
        sd[t] += v;
        __syncthreads();
    }
    int ex = sd[t] - s;
    if (i0+0 < N) row_start[i0+0] = ex;
    if (i0+1 < N) row_start[i0+1] = ex + c0;
    if (i0+2 < N) row_start[i0+2] = ex + c0 + c1;
    if (i0+3 < N) row_start[i0+3] = ex + c0 + c1 + c2;
    if (t == 255) bsums[blockIdx.x] = sd[255];
}

__global__ __launch_bounds__(128) void scan2_kernel(int* __restrict__ bsums, int NB)
{
    __shared__ int sd[128];
    int t = threadIdx.x;
    int v = (t < NB) ? bsums[t] : 0;
    sd[t] = v;
    __syncthreads();
    #pragma unroll
    for (int off = 1; off < 128; off <<= 1) {
        int u = (t >= off) ? sd[t - off] : 0;
        __syncthreads();
        sd[t] += u;
        __syncthreads();
    }
    if (t < NB) bsums[t] = sd[t] - v;
}

__global__ __launch_bounds__(256) void scan3_kernel(
    int* __restrict__ row_start, const int* __restrict__ bsums,
    int* __restrict__ cursor, int N)
{
    int i = blockIdx.x * blockDim.x + threadIdx.x;
    if (i < N) {
        int r = row_start[i] + bsums[i >> 10];
        row_start[i] = r;
        cursor[i]    = r;
    }
}

// edat[p] = {edge id, dst}
__global__ __launch_bounds__(256) void fill_kernel(
    const int* __restrict__ eidx, int* __restrict__ cursor,
    int2* __restrict__ edat, int E)
{
    int e = blockIdx.x * blockDim.x + threadIdx.x;
    if (e < E) {
        int s = eidx[e];
        int p = atomicAdd(&cursor[s], 1);
        edat[p] = make_int2(e, eidx[E + e]);
    }
}

// ---------------------------------------------------------------------------
// out[v] = LN( x[v] + sum_{e: src=v} conv_bf16[dst]*eattr[e] )
// One wave per node; each 32-lane HALF processes its own edge stream with
// float4/ushort4 (16B/8B) loads -> 4 independent edge chains in flight/wave.
// ---------------------------------------------------------------------------
__global__ __launch_bounds__(256) void gather_ln_kernel(
    const float* __restrict__ x, const unsigned short* __restrict__ convb,
    const float* __restrict__ eattr,
    const int* __restrict__ row_start, const int2* __restrict__ edat,
    const float* __restrict__ g, const float* __restrict__ b,
    float* __restrict__ out, int N, int E)
{
    int node = blockIdx.x * 4 + (threadIdx.x >> 6);
    if (node >= N) return;
    int lane = threadIdx.x & 63;
    int half = lane >> 5;           // 0 or 1: which edge stream
    int c4   = (lane & 31) * 4;     // 4 consecutive cols per lane

    float4 acc = make_float4(0.f, 0.f, 0.f, 0.f);
    int je = (node + 1 < N) ? row_start[node + 1] : E;
    int j  = row_start[node] + half;

    // unroll 2 edges per half (j, j+2), step 4
    for (; j + 2 < je; j += 4) {
        int2 ea = edat[j];
        int2 eb = edat[j + 2];
        ushort4 ca = *(const ushort4*)(convb + (size_t)ea.y * D + c4);
        float4  aa = *(const float4*) (eattr + (size_t)ea.x * D + c4);
        ushort4 cb = *(const ushort4*)(convb + (size_t)eb.y * D + c4);
        float4  ab = *(const float4*) (eattr + (size_t)eb.x * D + c4);
        acc.x += bf2f(ca.x) * aa.x; acc.y += bf2f(ca.y) * aa.y;
        acc.z += bf2f(ca.z) * aa.z; acc.w += bf2f(ca.w) * aa.w;
        acc.x += bf2f(cb.x) * ab.x; acc.y += bf2f(cb.y) * ab.y;
        acc.z += bf2f(cb.z) * ab.z; acc.w += bf2f(cb.w) * ab.w;
    }
    if (j < je) {
        int2 ea = edat[j];
        ushort4 ca = *(const ushort4*)(convb + (size_t)ea.y * D + c4);
        float4  aa = *(const float4*) (eattr + (size_t)ea.x * D + c4);
        acc.x += bf2f(ca.x) * aa.x; acc.y += bf2f(ca.y) * aa.y;
        acc.z += bf2f(ca.z) * aa.z; acc.w += bf2f(ca.w) * aa.w;
    }

    // x contribution once (half 0), then combine halves
    if (half == 0) {
        float4 xv = *(const float4*)(x + (size_t)node * D + c4);
        acc.x += xv.x; acc.y += xv.y; acc.z += xv.z; acc.w += xv.w;
    }
    acc.x += __shfl_xor(acc.x, 32);
    acc.y += __shfl_xor(acc.y, 32);
    acc.z += __shfl_xor(acc.z, 32);
    acc.w += __shfl_xor(acc.w, 32);

    float s1 = acc.x + acc.y + acc.z + acc.w;
    float s2 = acc.x*acc.x + acc.y*acc.y + acc.z*acc.z + acc.w*acc.w;
    #pragma unroll
    for (int o = 1; o < 32; o <<= 1) {
        s1 += __shfl_xor(s1, o);
        s2 += __shfl_xor(s2, o);
    }
    float mu  = s1 * (1.f / D);
    float var = s2 * (1.f / D) - mu * mu;
    float rs  = rsqrtf(var + EPS);
    if (half == 0) {
        float4 gv = *(const float4*)(g + c4);
        float4 bv = *(const float4*)(b + c4);
        float4 o4;
        o4.x = (acc.x - mu) * rs * gv.x + bv.x;
        o4.y = (acc.y - mu) * rs * gv.y + bv.y;
        o4.z = (acc.z - mu) * rs * gv.z + bv.z;
        o4.w = (acc.w - mu) * rs * gv.w + bv.w;
        *(float4*)(out + (size_t)node * D + c4) = o4;
    }
}

extern "C" void kernel_launch(void* const* d_in, const int* in_sizes, int n_in,
                              void* d_out, int out_size, void* d_ws, size_t ws_size,
                              hipStream_t stream) {
    const float* x     = (const float*)d_in[0];
    const int*   eidx  = (const int*)  d_in[1];
    const float* eattr = (const float*)d_in[2];
    const float* W1    = (const float*)d_in[3];
    const float* b1    = (const float*)d_in[4];
    const float* g1    = (const float*)d_in[5];
    const float* be1   = (const float*)d_in[6];
    const float* W2    = (const float*)d_in[7];
    const float* b2    = (const float*)d_in[8];
    const float* g2    = (const float*)d_in[9];
    const float* be2   = (const float*)d_in[10];
    const float* g_out = (const float*)d_in[11];
    const float* b_out = (const float*)d_in[12];

    const int N = in_sizes[0] / D;   // 100000
    const int E = in_sizes[1] / 2;   // 640000

    float* out = (float*)d_out;

    // workspace layout (256B aligned)
    auto align_up = [](size_t v) { return (v + 255) & ~(size_t)255; };
    size_t convB = align_up((size_t)N * D * sizeof(unsigned short));  // 25.6 MB
    size_t cntB  = align_up((size_t)N * sizeof(int));
    size_t rsB   = align_up((size_t)N * sizeof(int));
    size_t bsB   = align_up(128 * sizeof(int));
    size_t edB   = align_up((size_t)E * sizeof(int2));                // 5.12 MB
    size_t w1B   = align_up((size_t)D * H * sizeof(unsigned short));  // 64 KB

    char* w = (char*)d_ws;
    unsigned short* convb     = (unsigned short*)(w);
    int*            counts    = (int*)(w + convB);                 // reused as cursor
    int*            row_start = (int*)(w + convB + cntB);
    int*            bsums     = (int*)(w + convB + cntB + rsB);
    int2*           edat      = (int2*)(w + convB + cntB + rsB + bsB);
    unsigned short* W1p       = (unsigned short*)(w + convB + cntB + rsB + bsB + edB);
    unsigned short* W2p       = (unsigned short*)(w + convB + cntB + rsB + bsB + edB + w1B);

    // 1) pack weights into MFMA fragment order (bf16)
    pack_w_kernel<<<(D * H + 255) / 256, 256, 0, stream>>>(W1, W1p, D, H);
    pack_w_kernel<<<(H * D + 255) / 256, 256, 0, stream>>>(W2, W2p, H, D);

    // 2) conv = MLP(x) via bf16 MFMA
    conv_mlp_mfma<<<(N + 63) / 64, 256, 0, stream>>>(
        x, W1p, b1, g1, be1, W2p, b2, g2, be2, convb, N);

    // 3) CSR build
    zero_int_kernel<<<(N + 255) / 256, 256, 0, stream>>>(counts, N);
    hist_kernel<<<(E + 255) / 256, 256, 0, stream>>>(eidx, counts, E);
    int NB = (N + 1023) / 1024;
    scan1_kernel<<<NB, 256, 0, stream>>>(counts, row_start, bsums, N);
    scan2_kernel<<<1, 128, 0, stream>>>(bsums, NB);
    scan3_kernel<<<(N + 255) / 256, 256, 0, stream>>>(row_start, bsums, counts, N);
    fill_kernel<<<(E + 255) / 256, 256, 0, stream>>>(eidx, counts, edat, E);

    // 4) gather + final LN
    gather_ln_kernel<<<(N + 3) / 4, 256, 0, stream>>>(
        x, convb, eattr, row_start, edat, g_out, b_out, out, N, E);
}